// Round 9
// baseline (257.082 us; speedup 1.0000x reference)
//
#include <hip/hip_runtime.h>
#include <stdint.h>

// Problem constants
#define L_   3969         // patches
#define LP   3972         // padded L (mult of 4, for float4 loads)
#define EPS_ 1e-5f
#define LOG2E 1.4426950408889634f
#define MH   6            // split over im (patch-row chunks) in K3
#define IMR  11           // im rows per chunk (6*11 >= 63)
#define PLANE 254208      // LP*64 elements per tok plane (u16)

// workspace layout (float offsets). Total 6,720,608 floats = 26.9 MB
#define OFF_MF   0          // [2][64][LP] fg mean
#define OFF_SF   508416     // fg var
#define OFF_MB   1016832    // bg mean (dead after k2 -> SB bf16 tiles, by k1s)
#define OFF_SB   1525248    // bg var f32 (dead after k1s -> TF bf16 planes, by k2r)
#define OFF_TOKF 2033664    // PART slice kc=0 (f32 toks from k2)
#define OFF_TOKB 2542080
#define OFF_PACC 3050496    // [MH][2 b][LP][64]; == PART slices kc=1..3 (dead until k3)
#define OFF_PM   6100992    // [MH][2][LP]
#define OFF_PD   6148656
#define OFF_WT   6196320    // weights (dead after k2 -> TB bf16 planes, by k2r)
#define PART_SLICE 1016832  // floats per kc slice: [2 t][2 b][LP][64]

// fold coefficients (written by k3c AFTER k3b; these regions are dead by then)
#define OFF_A    2033664    // = OFF_TOKF  [2 b][64 c][LP]
#define OFF_B    2542080    // = OFF_TOKB
#define OFF_C    4067328    // = OFF_PACC + 2*508416 (PACC p=2 slice, dead after k3b)

typedef __attribute__((ext_vector_type(8))) short bf16x8;   // 8 bf16 (4 VGPRs)
typedef __attribute__((ext_vector_type(4))) float f32x4;    // MFMA accumulator

__device__ __forceinline__ uint16_t bf16_rne(float f) {
    uint32_t u = __float_as_uint(f);
    return (uint16_t)((u + 0x7FFFu + ((u >> 16) & 1u)) >> 16);
}
// hi = truncated top-16 bits (exact), lo = RNE(residual): hi+lo ~ 2^-17 relative
__device__ __forceinline__ void split_bf16(float v, uint16_t& h, uint16_t& l) {
    uint32_t u = __float_as_uint(v);
    uint32_t hu = u & 0xFFFF0000u;
    h = (uint16_t)(hu >> 16);
    l = bf16_rne(v - __uint_as_float(hu));
}
__device__ __forceinline__ uint4 pack8(const uint16_t* s) {
    uint4 r;
    r.x = (uint32_t)s[0] | ((uint32_t)s[1] << 16);
    r.y = (uint32_t)s[2] | ((uint32_t)s[3] << 16);
    r.z = (uint32_t)s[4] | ((uint32_t)s[5] << 16);
    r.w = (uint32_t)s[6] | ((uint32_t)s[7] << 16);
    return r;
}
// pair packers: elem a -> low16, elem b -> high16
// pkhi2 = single v_perm_b32: result = (a>>16) | (b & 0xFFFF0000)  (bit-identical)
__device__ __forceinline__ uint32_t pkhi2(float a, float b) {
    return __builtin_amdgcn_perm(__float_as_uint(b), __float_as_uint(a), 0x07060302u);
}
__device__ __forceinline__ uint32_t pklo2(float a, float b) {
    float ra = a - __uint_as_float(__float_as_uint(a) & 0xFFFF0000u);
    float rb = b - __uint_as_float(__float_as_uint(b) & 0xFFFF0000u);
    uint32_t r;
    asm("v_cvt_pk_bf16_f32 %0, %1, %2" : "=v"(r) : "v"(ra), "v"(rb));
    return r;
}

// ---------------- K0: weights -> split-bf16 MFMA A-fragment layout ----------------
__global__ void k0_w2(const float* __restrict__ wf, const float* __restrict__ wb,
                      float* __restrict__ ws) {
    int c = blockIdx.x, t = blockIdx.y;
    const float* w = t ? wb : wf;
    uint16_t* w2 = (uint16_t*)(ws + OFF_WT);
    int tid = threadIdx.x;
    int lane = tid & 63, dq = tid >> 6;
    int d = dq * 16 + (lane & 15), quad = lane >> 4;
    for (int kci = 0; kci < 2; ++kci) {
        int k = kci * 32 + quad * 8;
        const float* src = w + (size_t)(d * 64 + c) * 64 + k;
        uint16_t hb[8], lb[8];
#pragma unroll
        for (int j = 0; j < 8; ++j) split_bf16(src[j], hb[j], lb[j]);
        size_t base = ((size_t)(((t * 64 + c) * 2 + kci) * 4 + dq) * 2) * 512 + lane * 8;
        *(uint4*)(w2 + base) = pack8(hb);
        *(uint4*)(w2 + base + 512) = pack8(lb);
    }
}

// ---------------- K1: per-patch fg/bg stats ----------------
__global__ void k1_stats(const float* __restrict__ x, const float* __restrict__ mask,
                         float* __restrict__ ws) {
    int i = blockIdx.x, c = blockIdx.y, b = blockIdx.z;
    __shared__ float xs[8 * 256];
    __shared__ float ms[8 * 256];
    __shared__ float pS[5][256];
    int t = threadIdx.x;
    const float* xr = x + (((b * 64 + c) * 256) + i * 4) * 256;
    const float* mr = mask + (b * 256 + i * 4) * 256;
#pragma unroll
    for (int r = 0; r < 8; ++r) {
        xs[r * 256 + t] = xr[r * 256 + t];
        ms[r * 256 + t] = mr[r * 256 + t];
    }
    __syncthreads();
    int q = t >> 6, j = t & 63;
    float Sa = 0, Qa = 0, Sf = 0, Qf = 0, Nf = 0;
    if (j < 63) {
#pragma unroll
        for (int rr = 0; rr < 2; ++rr) {
            int base = (q * 2 + rr) * 256 + j * 4;
#pragma unroll
            for (int cc = 0; cc < 8; ++cc) {
                float v = xs[base + cc], m = ms[base + cc];
                Sa += v; Qa += v * v; Sf += v * m; Qf += v * v * m; Nf += m;
            }
        }
    }
    pS[0][t] = Sa; pS[1][t] = Qa; pS[2][t] = Sf; pS[3][t] = Qf; pS[4][t] = Nf;
    __syncthreads();
    if (q == 0 && j < 63) {
        Sa = pS[0][j] + pS[0][j + 64] + pS[0][j + 128] + pS[0][j + 192];
        Qa = pS[1][j] + pS[1][j + 64] + pS[1][j + 128] + pS[1][j + 192];
        Sf = pS[2][j] + pS[2][j + 64] + pS[2][j + 128] + pS[2][j + 192];
        Qf = pS[3][j] + pS[3][j + 64] + pS[3][j + 128] + pS[3][j + 192];
        Nf = pS[4][j] + pS[4][j + 64] + pS[4][j + 128] + pS[4][j + 192];
        float nb = 64.0f - Nf;
        float muf = Sf / (Nf + EPS_);
        float vaf = (Qf - 2.f * muf * Sf + Nf * muf * muf) / (Nf + EPS_);
        float Sb = Sa - Sf, Qb = Qa - Qf;
        float mub = Sb / (nb + EPS_);
        float vab = (Qb - 2.f * mub * Sb + nb * mub * mub) / (nb + EPS_);
        int idx = (b * 64 + c) * LP + i * 63 + j;
        ws[OFF_MF + idx] = muf; ws[OFF_SF + idx] = vaf;
        ws[OFF_MB + idx] = mub; ws[OFF_SB + idx] = vab;
    }
}

// ---------------- K2: split-bf16 MFMA tok GEMM, t-phase split ----------------
// grid (63 il, 4 kc, 2 b), 256 threads. Each channel processed in two phases
// (F-GEMM then B-GEMM); per-phase LDS = 2 planes (18 KB); buf0=F, buf1=B ->
// 36 KB total -> 4 blocks/CU (2x the old occupancy). x prefetch is 2 channels
// deep (two xa register slots) so HBM latency stays covered by ~3 phases.
__global__ __launch_bounds__(256, 4)
void k2_tok(const float* __restrict__ x, const float* __restrict__ mask,
            const float* __restrict__ wsc, float* __restrict__ ws) {
    int il = blockIdx.x, kc = blockIdx.y, b = blockIdx.z;
    int tid = threadIdx.x;
    int jl = tid & 63;
    int q = tid >> 6;
    __shared__ uint16_t IN[2][2 * 64 * 72];   // [stream t][hl plane][l 64][k 72pad]
    const uint16_t* w2 = (const uint16_t*)(wsc + OFF_WT);

    bool lv = jl < 63;
    int lg = il * 63 + jl;

    uint32_t mbits[2] = {0u, 0u};
    if (lv) {
#pragma unroll
        for (int oi = 0; oi < 2; ++oi) {
            int o = q + oi * 4;
            const float* mp = mask + (size_t)b * 65536 + (il * 4 + o) * 256 + jl * 4;
            float4 m0 = *(const float4*)mp;
            float4 m1 = *(const float4*)(mp + 4);
            uint32_t bits = 0;
            bits |= (m0.x != 0.f) ? 1u : 0u;  bits |= (m0.y != 0.f) ? 2u : 0u;
            bits |= (m0.z != 0.f) ? 4u : 0u;  bits |= (m0.w != 0.f) ? 8u : 0u;
            bits |= (m1.x != 0.f) ? 16u : 0u; bits |= (m1.y != 0.f) ? 32u : 0u;
            bits |= (m1.z != 0.f) ? 64u : 0u; bits |= (m1.w != 0.f) ? 128u : 0u;
            mbits[oi] = bits;
        }
    }

    f32x4 acc[2][2][2];   // [t][dqi][lt]
#pragma unroll
    for (int t = 0; t < 2; ++t)
#pragma unroll
        for (int i2 = 0; i2 < 2; ++i2)
#pragma unroll
            for (int j2 = 0; j2 < 2; ++j2) acc[t][i2][j2] = (f32x4)(0.f);

    int lane = tid & 63;
    int quad = lane >> 4;
    int c16 = lane & 15;
    int wd = q >> 1, wl = q & 1;   // wave tile: d half, l half
    int c0 = kc * 16;

    // two-deep channel pipeline registers (slot = ci & 1)
    float4 xa[2][2][2];   // [slot][oi][half]
    float muF[2] = {0.f, 0.f}, vaF[2] = {1.f, 1.f};
    float muB[2] = {0.f, 0.f}, vaB[2] = {1.f, 1.f};
    if (!lv) {
#pragma unroll
        for (int sl = 0; sl < 2; ++sl)
#pragma unroll
            for (int oi = 0; oi < 2; ++oi)
#pragma unroll
                for (int hf = 0; hf < 2; ++hf)
                    xa[sl][oi][hf] = make_float4(0.f, 0.f, 0.f, 0.f);
    }

#define K2_LOADCH(sl, cc)                                                            \
    do {                                                                             \
        if (lv) {                                                                    \
            int si = (b * 64 + (cc)) * LP + lg;                                      \
            muF[sl] = wsc[OFF_MF + si]; vaF[sl] = wsc[OFF_SF + si];                  \
            muB[sl] = wsc[OFF_MB + si]; vaB[sl] = wsc[OFF_SB + si];                  \
            const float* xp0 = x + (size_t)(b * 64 + (cc)) * 65536 + (il * 4 + q) * 256 + jl * 4; \
            xa[sl][0][0] = *(const float4*)xp0;                                      \
            xa[sl][0][1] = *(const float4*)(xp0 + 4);                                \
            xa[sl][1][0] = *(const float4*)(xp0 + 1024);                             \
            xa[sl][1][1] = *(const float4*)(xp0 + 1028);                             \
        }                                                                            \
    } while (0)

    // pack stream ts (0=F, 1=B) of slot sl into buffer IN[ts]
#define K2_PACKT(ts, sl)                                                             \
    do {                                                                             \
        float va_ = (ts) ? vaB[sl] : vaF[sl];                                        \
        float mu_ = (ts) ? muB[sl] : muF[sl];                                        \
        float inv_ = lv ? (1.0f / va_) : 0.f;                                        \
        float cm_ = lv ? mu_ : 0.f;                                                  \
        _Pragma("unroll")                                                            \
        for (int oi = 0; oi < 2; ++oi) {                                             \
            float xv[8];                                                             \
            xv[0] = xa[sl][oi][0].x; xv[1] = xa[sl][oi][0].y;                        \
            xv[2] = xa[sl][oi][0].z; xv[3] = xa[sl][oi][0].w;                        \
            xv[4] = xa[sl][oi][1].x; xv[5] = xa[sl][oi][1].y;                        \
            xv[6] = xa[sl][oi][1].z; xv[7] = xa[sl][oi][1].w;                        \
            float fv[8];                                                             \
            _Pragma("unroll")                                                        \
            for (int j = 0; j < 8; ++j) {                                            \
                bool mf = (mbits[oi] >> j) & 1;                                      \
                float v = xv[j];                                                     \
                float nrm = (v - cm_) * inv_;                                        \
                fv[j] = (ts) ? (mf ? cm_ : nrm) : (mf ? nrm : cm_);                  \
            }                                                                        \
            uint4 H, L;                                                              \
            H.x = pkhi2(fv[0], fv[1]); H.y = pkhi2(fv[2], fv[3]);                    \
            H.z = pkhi2(fv[4], fv[5]); H.w = pkhi2(fv[6], fv[7]);                    \
            L.x = pklo2(fv[0], fv[1]); L.y = pklo2(fv[2], fv[3]);                    \
            L.z = pklo2(fv[4], fv[5]); L.w = pklo2(fv[6], fv[7]);                    \
            uint16_t* dst = &IN[ts][jl * 72 + (q + oi * 4) * 8];                     \
            *(uint4*)(dst)        = H;                                               \
            *(uint4*)(dst + 4608) = L;                                               \
        }                                                                            \
    } while (0)

    // MFMA stream ts of channel cch from buffer IN[ts] (24 MFMAs)
#define K2_MFMAT(ts, cch)                                                            \
    do {                                                                             \
        _Pragma("unroll")                                                            \
        for (int kci = 0; kci < 2; ++kci) {                                          \
            bf16x8 Ah[2], Al[2];                                                     \
            _Pragma("unroll")                                                        \
            for (int dqi = 0; dqi < 2; ++dqi) {                                      \
                const uint16_t* ab = w2 +                                            \
                    ((size_t)((((ts) * 64 + (cch)) * 2 + kci) * 4 + (wd * 2 + dqi)) * 2) * 512 + lane * 8; \
                Ah[dqi] = *(const bf16x8*)ab;                                        \
                Al[dqi] = *(const bf16x8*)(ab + 512);                                \
            }                                                                        \
            _Pragma("unroll")                                                        \
            for (int lt = 0; lt < 2; ++lt) {                                         \
                const uint16_t* bp = &IN[ts][(wl * 32 + lt * 16 + c16) * 72 + kci * 32 + quad * 8]; \
                bf16x8 Bh = *(const bf16x8*)bp;                                      \
                bf16x8 Bl = *(const bf16x8*)(bp + 4608);                             \
                _Pragma("unroll")                                                    \
                for (int dqi = 0; dqi < 2; ++dqi) {                                  \
                    acc[ts][dqi][lt] = __builtin_amdgcn_mfma_f32_16x16x32_bf16(Ah[dqi], Bh, acc[ts][dqi][lt], 0, 0, 0); \
                    acc[ts][dqi][lt] = __builtin_amdgcn_mfma_f32_16x16x32_bf16(Ah[dqi], Bl, acc[ts][dqi][lt], 0, 0, 0); \
                    acc[ts][dqi][lt] = __builtin_amdgcn_mfma_f32_16x16x32_bf16(Al[dqi], Bh, acc[ts][dqi][lt], 0, 0, 0); \
                }                                                                    \
            }                                                                        \
        }                                                                            \
    } while (0)

    // prologue: ch0 -> slot0, pack F(ch0); ch1 -> slot1
    K2_LOADCH(0, c0);
    K2_PACKT(0, 0);
    K2_LOADCH(1, c0 + 1);
    __syncthreads();

#pragma unroll 2
    for (int ci = 0; ci < 16; ++ci) {
        int sl = ci & 1;
        // phase A: pack B(ci) -> buf1; prefetch ci+2 -> slot sl; MFMA F(ci) from buf0
        K2_PACKT(1, sl);
        if (ci < 14) K2_LOADCH(sl, c0 + ci + 2);
        K2_MFMAT(0, c0 + ci);
        __syncthreads();
        // phase B: pack F(ci+1) -> buf0 (slot sl^1, loaded 2 phases ago); MFMA B(ci) from buf1
        if (ci < 15) K2_PACKT(0, sl ^ 1);
        K2_MFMAT(1, c0 + ci);
        __syncthreads();
    }
#undef K2_LOADCH
#undef K2_PACKT
#undef K2_MFMAT

    // ---- epilogue: LDS transpose -> coalesced float4 stores to PART (no atomics) ----
    // C/D 16x16: row(d within tile)=quad*4+r, col(l within tile)=lane&15
    float* ST = (float*)&IN[0][0];   // 64 l x 68 d floats = 17.4 KB, fits in 36 KB
#pragma unroll
    for (int t = 0; t < 2; ++t) {
        __syncthreads();
#pragma unroll
        for (int dqi = 0; dqi < 2; ++dqi)
#pragma unroll
            for (int lt = 0; lt < 2; ++lt)
#pragma unroll
                for (int r = 0; r < 4; ++r)
                    ST[(wl * 32 + lt * 16 + c16) * 68 + (wd * 2 + dqi) * 16 + quad * 4 + r] =
                        acc[t][dqi][lt][r];
        __syncthreads();
        float* dst = ws + OFF_TOKF + (size_t)kc * PART_SLICE + ((t * 2 + b) * (size_t)LP) * 64;
        int d4 = (tid & 15) * 4;
#pragma unroll
        for (int pass = 0; pass < 4; ++pass) {
            int l = pass * 16 + (tid >> 4);
            if (l < 63)
                *(float4*)&dst[(size_t)(il * 63 + l) * 64 + d4] = *(float4*)&ST[l * 68 + d4];
        }
    }
}

// ---------------- K2r: reduce 4 kc partial slices -> separated bf16 planes ----------------
// TF planes (t=0): [b*2+hl][PLANE] u16 at OFF_SB  (SB f32 dead after k1s; exact fit)
// TB planes (t=1): [b*2+hl][PLANE] u16 at OFF_WT  (weights dead after k2; fits)
__global__ void k2r_reduce(float* __restrict__ ws) {
    size_t e = ((size_t)blockIdx.x * 256 + threadIdx.x) * 4;
    float4 a0 = *(float4*)&ws[OFF_TOKF + e];
    float4 a1 = *(float4*)&ws[OFF_TOKF + PART_SLICE + e];
    float4 a2 = *(float4*)&ws[OFF_TOKF + 2 * PART_SLICE + e];
    float4 a3 = *(float4*)&ws[OFF_TOKF + 3 * PART_SLICE + e];
    float s0 = a0.x + a1.x + a2.x + a3.x;
    float s1 = a0.y + a1.y + a2.y + a3.y;
    float s2 = a0.z + a1.z + a2.z + a3.z;
    float s3 = a0.w + a1.w + a2.w + a3.w;
    int tb = (int)(e / (size_t)PLANE);           // t*2+b  (element order is [t][b][LP][64])
    int idx = (int)(e - (size_t)tb * PLANE);
    int t = tb >> 1, b = tb & 1;
    uint16_t* pl = (uint16_t*)(ws + (t ? OFF_WT : OFF_SB));
    uint2 hv, lv;
    hv.x = pkhi2(s0, s1); hv.y = pkhi2(s2, s3);
    lv.x = pklo2(s0, s1); lv.y = pklo2(s2, s3);
    *(uint2*)&pl[(size_t)(b * 2 + 0) * PLANE + idx] = hv;
    *(uint2*)&pl[(size_t)(b * 2 + 1) * PLANE + idx] = lv;
}

// ---------------- K1s: SB variances -> bf16 tiles [b][im][c][64] (m=63 zeroed) ----------
// Runs after k2 (which reads MB/SB f32) and BEFORE k2r (which overwrites SB f32).
__global__ void k1s_sb(float* __restrict__ ws) {
    int im = blockIdx.x, b = blockIdx.y;
    int tid = threadIdx.x;
    int c = tid >> 2, mm = (tid & 3) * 16;
    const float* src = ws + OFF_SB + ((size_t)b * 64 + c) * LP + im * 63 + mm;
    uint16_t sv[16];
#pragma unroll
    for (int u = 0; u < 16; ++u)
        sv[u] = (mm + u < 63) ? bf16_rne(src[u]) : (uint16_t)0;
    uint16_t* dst = (uint16_t*)(ws + OFF_MB) + (((size_t)b * 63 + im) * 64 + c) * 64 + mm;
    *(uint4*)(dst) = pack8(sv);
    *(uint4*)(dst + 8) = pack8(sv + 8);
}

// ---------------- K3: swapped-QK^T MFMA flash attention ----------------
// grid (63 il, MH imc, 2 b), 256 threads, 4 blocks/CU (37.4 KB LDS).
// Q (tok_f) fragments live in registers (wave-private rows). QK^T computes
// mfma(A=keys, B=queries) so each lane owns one query's score row -> softmax
// reduce = in-lane tree + 2 shfls (vs 32 shfls). P has a dedicated wave-private
// LDS buffer -> only 2 barriers/iter. T14 prefetch retained.
__global__ __launch_bounds__(256, 4)
void k3_attn(const float* __restrict__ wsc, const float* __restrict__ rpb,
             float* __restrict__ ws) {
    int il = blockIdx.x, imc = blockIdx.y, b = blockIdx.z;
    int tid = threadIdx.x;
    int w = tid >> 6, lane = tid & 63;
    int c16 = lane & 15, quad = lane >> 4;

    __shared__ uint16_t TBh[64 * 72];   // tok_b hi [m][c]
    __shared__ uint16_t TBl[64 * 72];   // tok_b lo
    __shared__ uint16_t SB[64 * 72];    // sb [c][m] bf16
    __shared__ uint16_t P[64 * 72];     // P [query][m] (wave-private 16-row stripes)
    __shared__ float bias_r[128];

    const uint16_t* tfp = (const uint16_t*)(wsc + OFF_SB);
    const uint16_t* tbp = (const uint16_t*)(wsc + OFF_WT);
    const uint16_t* TFH = tfp + (size_t)(b * 2 + 0) * PLANE;
    const uint16_t* TFL = tfp + (size_t)(b * 2 + 1) * PLANE;
    const uint16_t* TBH = tbp + (size_t)(b * 2 + 0) * PLANE;
    const uint16_t* TBL = tbp + (size_t)(b * 2 + 1) * PLANE;
    const uint16_t* sbb = (const uint16_t*)(wsc + OFF_MB);    // [b][im][c][64] bf16

    // Q fragments (B-operand rows = query = lane&15), loaded once from planes.
    int qrow = il * 63 + w * 16 + c16;   // rows 3969..3971 garbage only for discarded query
    bf16x8 Qh[2], Ql[2];
#pragma unroll
    for (int kk = 0; kk < 2; ++kk) {
        Qh[kk] = *(const bf16x8*)&TFH[(size_t)qrow * 64 + kk * 32 + quad * 8];
        Ql[kk] = *(const bf16x8*)&TFL[(size_t)qrow * 64 + kk * 32 + quad * 8];
    }

    float mrun = -1e30f, drun = 0.f;     // per-lane: one query (w*16+c16)
    f32x4 acc2[4];
#pragma unroll
    for (int ct = 0; ct < 4; ++ct) acc2[ct] = (f32x4)(0.f);

    int im0 = imc * IMR;
    int im1 = min(63, im0 + IMR);

    // T14 prefetch registers
    int jms = tid >> 2, ccs = (tid & 3) * 16;
    uint4 rTH0, rTH1, rTL0, rTL1, rS0, rS1;
    float rBias;

#define K3_PREFETCH(imv)                                                              \
    do {                                                                              \
        if (jms < 63) {                                                               \
            const uint16_t* sh_ = TBH + (size_t)((imv) * 63 + jms) * 64 + ccs;        \
            const uint16_t* sl_ = TBL + (size_t)((imv) * 63 + jms) * 64 + ccs;        \
            rTH0 = *(const uint4*)sh_; rTH1 = *(const uint4*)(sh_ + 8);               \
            rTL0 = *(const uint4*)sl_; rTL1 = *(const uint4*)(sl_ + 8);               \
        } else {                                                                      \
            rTH0 = rTH1 = rTL0 = rTL1 = make_uint4(0u,0u,0u,0u);                      \
        }                                                                             \
        const uint16_t* ss_ = sbb + (((size_t)b * 63 + (imv)) * 64 + jms) * 64 + ccs; \
        rS0 = *(const uint4*)ss_; rS1 = *(const uint4*)(ss_ + 8);                     \
        rBias = (tid < 125) ? rpb[(il - (imv) + 62) * 125 + tid] : 0.f;               \
    } while (0)

    K3_PREFETCH(im0);

    int ibias = w * 16 + c16 + 62 - quad * 4;   // bias idx = ibias - jt*16 - r

    for (int im = im0; im < im1; ++im) {
        __syncthreads();   // previous tile's readers done
        *(uint4*)&TBh[jms * 72 + ccs] = rTH0; *(uint4*)&TBh[jms * 72 + ccs + 8] = rTH1;
        *(uint4*)&TBl[jms * 72 + ccs] = rTL0; *(uint4*)&TBl[jms * 72 + ccs + 8] = rTL1;
        *(uint4*)&SB[jms * 72 + ccs]  = rS0;  *(uint4*)&SB[jms * 72 + ccs + 8]  = rS1;
        if (tid < 128) bias_r[tid] = rBias;
        if (im + 1 < im1) K3_PREFETCH(im + 1);
        __syncthreads();

        // ---- QK^T swapped: A = keys (LDS), B = queries (regs) ----
        // D rows = m (quad*4+r per 16-tile jt), cols = query (c16)
        f32x4 Z[4];
#pragma unroll
        for (int jt = 0; jt < 4; ++jt) Z[jt] = (f32x4)(0.f);
#pragma unroll
        for (int jt = 0; jt < 4; ++jt) {
#pragma unroll
            for (int kk = 0; kk < 2; ++kk) {
                bf16x8 Kh = *(bf16x8*)&TBh[(jt * 16 + c16) * 72 + kk * 32 + quad * 8];
                bf16x8 Kl = *(bf16x8*)&TBl[(jt * 16 + c16) * 72 + kk * 32 + quad * 8];
                Z[jt] = __builtin_amdgcn_mfma_f32_16x16x32_bf16(Kh, Qh[kk], Z[jt], 0, 0, 0);
                Z[jt] = __builtin_amdgcn_mfma_f32_16x16x32_bf16(Kh, Ql[kk], Z[jt], 0, 0, 0);
                Z[jt] = __builtin_amdgcn_mfma_f32_16x16x32_bf16(Kl, Qh[kk], Z[jt], 0, 0, 0);
            }
        }

        // ---- bias + mask: lane owns query w*16+c16, scores over m ----
        float zv[4][4];
#pragma unroll
        for (int jt = 0; jt < 4; ++jt)
#pragma unroll
            for (int r = 0; r < 4; ++r) {
                int m = jt * 16 + quad * 4 + r;
                int bi = ibias - jt * 16 - r;
                bi = bi < 0 ? 0 : bi;            // binds only on the masked (i=0,m=63) lane
                zv[jt][r] = (m == 63) ? -1e30f : (Z[jt][r] + bias_r[bi]);
            }

        // ---- softmax: in-lane tree + xor16/xor32 (c16-preserving) ----
        float a0 = fmaxf(zv[0][0], zv[0][1]), a1 = fmaxf(zv[0][2], zv[0][3]);
        float a2 = fmaxf(zv[1][0], zv[1][1]), a3 = fmaxf(zv[1][2], zv[1][3]);
        float a4 = fmaxf(zv[2][0], zv[2][1]), a5 = fmaxf(zv[2][2], zv[2][3]);
        float a6 = fmaxf(zv[3][0], zv[3][1]), a7 = fmaxf(zv[3][2], zv[3][3]);
        a0 = fmaxf(a0, a1); a2 = fmaxf(a2, a3); a4 = fmaxf(a4, a5); a6 = fmaxf(a6, a7);
        float vmax = fmaxf(fmaxf(a0, a2), fmaxf(a4, a6));
        vmax = fmaxf(vmax, __shfl_xor(vmax, 16));
        vmax = fmaxf(vmax, __shfl_xor(vmax, 32));
        float mnew = fmaxf(mrun, vmax);
        float alpha = exp2f((mrun - mnew) * LOG2E);
        uint16_t pb[4][4];
        float sv[8];
#pragma unroll
        for (int jt = 0; jt < 4; ++jt) {
            float p0 = exp2f((zv[jt][0] - mnew) * LOG2E);
            float p1 = exp2f((zv[jt][1] - mnew) * LOG2E);
            float p2 = exp2f((zv[jt][2] - mnew) * LOG2E);
            float p3 = exp2f((zv[jt][3] - mnew) * LOG2E);
            uint16_t h0 = bf16_rne(p0), h1 = bf16_rne(p1);
            uint16_t h2 = bf16_rne(p2), h3 = bf16_rne(p3);
            pb[jt][0] = h0; pb[jt][1] = h1; pb[jt][2] = h2; pb[jt][3] = h3;
            sv[jt * 2]     = __uint_as_float((uint32_t)h0 << 16) + __uint_as_float((uint32_t)h1 << 16);
            sv[jt * 2 + 1] = __uint_as_float((uint32_t)h2 << 16) + __uint_as_float((uint32_t)h3 << 16);
        }
        float s = ((sv[0] + sv[1]) + (sv[2] + sv[3])) + ((sv[4] + sv[5]) + (sv[6] + sv[7]));
        s += __shfl_xor(s, 16);
        s += __shfl_xor(s, 32);
        drun = drun * alpha + s;
        mrun = mnew;

        // redistribute alpha to accumulator row decomposition (D rows = quad*4+r)
        float alphav[4];
#pragma unroll
        for (int r = 0; r < 4; ++r) alphav[r] = __shfl(alpha, quad * 4 + r, 16);
#pragma unroll
        for (int ct = 0; ct < 4; ++ct)
#pragma unroll
            for (int r = 0; r < 4; ++r) acc2[ct][r] *= alphav[r];

        // ---- P write: row = query (w*16+c16), cols m; wave-private, packed b64 ----
#pragma unroll
        for (int jt = 0; jt < 4; ++jt) {
            uint2 pw;
            pw.x = (uint32_t)pb[jt][0] | ((uint32_t)pb[jt][1] << 16);
            pw.y = (uint32_t)pb[jt][2] | ((uint32_t)pb[jt][3] << 16);
            *(uint2*)&P[(w * 16 + c16) * 72 + jt * 16 + quad * 4] = pw;
        }
        asm volatile("" ::: "memory");

        // ---- PV: A = P (rows=query), B = SB (rows=channel) ----
#pragma unroll
        for (int kk = 0; kk < 2; ++kk) {
            bf16x8 Pf = *(bf16x8*)&P[(w * 16 + c16) * 72 + kk * 32 + quad * 8];
#pragma unroll
            for (int ct = 0; ct < 4; ++ct) {
                bf16x8 Sf = *(bf16x8*)&SB[(ct * 16 + c16) * 72 + kk * 32 + quad * 8];
                acc2[ct] = __builtin_amdgcn_mfma_f32_16x16x32_bf16(Pf, Sf, acc2[ct], 0, 0, 0);
            }
        }
        asm volatile("" ::: "memory");   // keep next iter's P writes after these reads
    }

    float* PA = ws + OFF_PACC + ((imc * 2 + b) * (size_t)LP) * 64;
#pragma unroll
    for (int r = 0; r < 4; ++r) {
        int i = w * 16 + quad * 4 + r;
        if (i < 63) {
            int rl = il * 63 + i;
#pragma unroll
            for (int ct = 0; ct < 4; ++ct)
                PA[(size_t)rl * 64 + ct * 16 + c16] = acc2[ct][r];
        }
    }
    if (quad == 0) {
        int i = w * 16 + c16;
        if (i < 63) {
            int rl = il * 63 + i;
            ws[OFF_PM + (imc * 2 + b) * LP + rl] = mrun;
            ws[OFF_PD + (imc * 2 + b) * LP + rl] = drun;
        }
    }
#undef K3_PREFETCH
}

// ---------------- K3b: merge the MH m-slices; result lands in PACC slice 0 ----------------
__global__ void k3b_merge(float* __restrict__ ws) {
    int b = blockIdx.y;
    int l = blockIdx.x * 4 + (threadIdx.x >> 6);
    int c = threadIdx.x & 63;
    if (l >= L_) return;
    float M = -1e30f;
#pragma unroll
    for (int p = 0; p < MH; ++p)
        M = fmaxf(M, ws[OFF_PM + (p * 2 + b) * LP + l]);
    float denom = 0.f, num = 0.f;
#pragma unroll
    for (int p = 0; p < MH; ++p) {
        float w = exp2f((ws[OFF_PM + (p * 2 + b) * LP + l] - M) * LOG2E);
        denom += ws[OFF_PD + (p * 2 + b) * LP + l] * w;
        num += ws[OFF_PACC + ((p * 2 + b) * (size_t)LP + l) * 64 + c] * w;
    }
    ws[OFF_PACC + (b * (size_t)LP + l) * 64 + c] = num / denom;
}

// ---------------- K3c: fold coefficients A = NS/SF, B = NS - MF*A, C = NS*(MF+1) ----------------
__global__ void k3c_coef(float* __restrict__ ws) {
    int b = blockIdx.y;
    int bl = blockIdx.x;
    int tid = threadIdx.x;
    __shared__ float T[3][4][65];
    int ls = tid >> 6, c = tid & 63;
    int l = bl * 4 + ls;
    float ns = ws[OFF_PACC + ((size_t)b * LP + l) * 64 + c];
    float mf = ws[OFF_MF + (size_t)(b * 64 + c) * LP + l];
    float sf = ws[OFF_SF + (size_t)(b * 64 + c) * LP + l];
    float a = ns / sf;
    T[0][ls][c] = a;
    T[1][ls][c] = ns - mf * a;
    T[2][ls][c] = ns * (mf + 1.f);
    __syncthreads();
    int c2 = tid >> 2, l2 = tid & 3;
    size_t o = (size_t)(b * 64 + c2) * LP + bl * 4 + l2;
    ws[OFF_A + o] = T[0][l2][c2];
    ws[OFF_B + o] = T[1][l2][c2];
    ws[OFF_C + o] = T[2][l2][c2];
}

// ---------------- K4: fold + affines + compose output (coefficient form, no divides) ----------------
__global__ void k4_fold(const float* __restrict__ x, const float* __restrict__ mask,
                        const float* __restrict__ fg_g, const float* __restrict__ fg_b,
                        const float* __restrict__ bg_g, const float* __restrict__ bg_b,
                        const float* __restrict__ wsc, float* __restrict__ out) {
    int gid = blockIdx.x * 256 + threadIdx.x;
    int col = gid & 255, r = (gid >> 8) & 255, c = (gid >> 16) & 63, b = gid >> 22;
    float xv = x[gid];
    float m = mask[b * 65536 + r * 256 + col];
    int imin = (r >= 4) ? ((r - 4) >> 2) : 0;
    int imax = min(62, r >> 2);
    int jmin = (col >= 4) ? ((col - 4) >> 2) : 0;
    int jmax = min(62, col >> 2);
    bool fi = imax > imin, fj = jmax > jmin;
    int l00 = imin * 63 + jmin;
    const float* Aa = wsc + OFF_A + (size_t)(b * 64 + c) * LP;
    const float* Ba = wsc + OFF_B + (size_t)(b * 64 + c) * LP;
    const float* Ca = wsc + OFF_C + (size_t)(b * 64 + c) * LP;
    float a00 = Aa[l00],      b00 = Ba[l00],      c00 = Ca[l00];
    float a01 = Aa[l00 + 1],  b01 = Ba[l00 + 1],  c01 = Ca[l00 + 1];
    float a10 = Aa[l00 + 63], b10 = Ba[l00 + 63], c10 = Ca[l00 + 63];
    float a11 = Aa[l00 + 64], b11 = Ba[l00 + 64], c11 = Ca[l00 + 64];
    bool fij = fi && fj;
    float SA = a00 + (fj ? a01 : 0.f) + (fi ? a10 : 0.f) + (fij ? a11 : 0.f);
    float SBv = b00 + (fj ? b01 : 0.f) + (fi ? b10 : 0.f) + (fij ? b11 : 0.f);
    float SCv = c00 + (fj ? c01 : 0.f) + (fi ? c10 : 0.f) + (fij ? c11 : 0.f);
    float folded = (m != 0.f) ? (xv * SA + SBv) : SCv;
    float rc = (fi ? 0.5f : 1.f) * (fj ? 0.5f : 1.f);
    float invm = 1.f - m;
    float ub = (xv * invm * (1.f + bg_g[c]) + bg_b[c]) * invm;
    float nf = (folded * rc * (1.f + fg_g[c]) + fg_b[c]) * m;
    out[gid] = nf + ub;
}

extern "C" void kernel_launch(void* const* d_in, const int* in_sizes, int n_in,
                              void* d_out, int out_size, void* d_ws, size_t ws_size,
                              hipStream_t stream) {
    const float* x    = (const float*)d_in[0];
    const float* mask = (const float*)d_in[1];
    const float* fg_g = (const float*)d_in[2];
    const float* fg_b = (const float*)d_in[3];
    const float* bg_g = (const float*)d_in[4];
    const float* bg_b = (const float*)d_in[5];
    const float* wf   = (const float*)d_in[6];
    const float* wb   = (const float*)d_in[7];
    const float* rpb  = (const float*)d_in[8];
    float* ws = (float*)d_ws;
    float* out = (float*)d_out;

    k0_w2<<<dim3(64, 2), 256, 0, stream>>>(wf, wb, ws);
    k1_stats<<<dim3(63, 64, 2), 256, 0, stream>>>(x, mask, ws);
    k2_tok<<<dim3(63, 4, 2), 256, 0, stream>>>(x, mask, ws, ws);
    k1s_sb<<<dim3(63, 2), 256, 0, stream>>>(ws);          // before k2r (k2r overwrites SB f32)
    k2r_reduce<<<dim3(993), 256, 0, stream>>>(ws);
    k3_attn<<<dim3(63, MH, 2), 256, 0, stream>>>(ws, rpb, ws);
    k3b_merge<<<dim3(993, 2), 256, 0, stream>>>(ws);
    k3c_coef<<<dim3(993, 2), 256, 0, stream>>>(ws);
    k4_fold<<<dim3(32768), 256, 0, stream>>>(x, mask, fg_g, fg_b, bg_g, bg_b, ws, out);
}

// Round 10
// 243.561 us; speedup vs baseline: 1.0555x; 1.0555x over previous
//
#include <hip/hip_runtime.h>
#include <stdint.h>

// Problem constants
#define L_   3969         // patches
#define LP   3972         // padded L (mult of 4, for float4 loads)
#define EPS_ 1e-5f
#define LOG2E 1.4426950408889634f
#define MH   6            // split over im (patch-row chunks) in K3
#define IMR  11           // im rows per chunk (6*11 >= 63)
#define PLANE 254208      // LP*64 elements per tok plane (u16)

// workspace layout (float offsets). Total 6,720,608 floats = 26.9 MB
#define OFF_MF   0          // [2][64][LP] fg mean
#define OFF_SF   508416     // fg var
#define OFF_MB   1016832    // bg mean (dead after k2 -> SB bf16 tiles, by k1s)
#define OFF_SB   1525248    // bg var f32 (dead after k1s -> TF bf16 planes, by k2r)
#define OFF_TOKF 2033664    // PART slice kc=0 (f32 toks from k2)
#define OFF_TOKB 2542080
#define OFF_PACC 3050496    // [MH][2 b][LP][64]; == PART slices kc=1..3 (dead until k3)
#define OFF_PM   6100992    // [MH][2][LP]
#define OFF_PD   6148656
#define OFF_WT   6196320    // weights (dead after k2 -> TB bf16 planes, by k2r)
#define PART_SLICE 1016832  // floats per kc slice: [2 t][2 b][LP][64]

// fold coefficients (written by k3c AFTER k3b; these regions are dead by then)
#define OFF_A    2033664    // = OFF_TOKF  [2 b][64 c][LP]
#define OFF_B    2542080    // = OFF_TOKB
#define OFF_C    4067328    // = OFF_PACC + 2*508416 (PACC p=2 slice, dead after k3b)

typedef __attribute__((ext_vector_type(8))) short bf16x8;   // 8 bf16 (4 VGPRs)
typedef __attribute__((ext_vector_type(4))) float f32x4;    // MFMA accumulator

__device__ __forceinline__ uint16_t bf16_rne(float f) {
    uint32_t u = __float_as_uint(f);
    return (uint16_t)((u + 0x7FFFu + ((u >> 16) & 1u)) >> 16);
}
// hi = truncated top-16 bits (exact), lo = RNE(residual): hi+lo ~ 2^-17 relative
__device__ __forceinline__ void split_bf16(float v, uint16_t& h, uint16_t& l) {
    uint32_t u = __float_as_uint(v);
    uint32_t hu = u & 0xFFFF0000u;
    h = (uint16_t)(hu >> 16);
    l = bf16_rne(v - __uint_as_float(hu));
}
__device__ __forceinline__ uint4 pack8(const uint16_t* s) {
    uint4 r;
    r.x = (uint32_t)s[0] | ((uint32_t)s[1] << 16);
    r.y = (uint32_t)s[2] | ((uint32_t)s[3] << 16);
    r.z = (uint32_t)s[4] | ((uint32_t)s[5] << 16);
    r.w = (uint32_t)s[6] | ((uint32_t)s[7] << 16);
    return r;
}
// pair packers: elem a -> low16, elem b -> high16
// pkhi2 = single v_perm_b32: result = (a>>16) | (b & 0xFFFF0000)  (bit-identical)
__device__ __forceinline__ uint32_t pkhi2(float a, float b) {
    return __builtin_amdgcn_perm(__float_as_uint(b), __float_as_uint(a), 0x07060302u);
}
__device__ __forceinline__ uint32_t pklo2(float a, float b) {
    float ra = a - __uint_as_float(__float_as_uint(a) & 0xFFFF0000u);
    float rb = b - __uint_as_float(__float_as_uint(b) & 0xFFFF0000u);
    uint32_t r;
    asm("v_cvt_pk_bf16_f32 %0, %1, %2" : "=v"(r) : "v"(ra), "v"(rb));
    return r;
}

// ---------------- K0: weights -> split-bf16 MFMA A-fragment layout ----------------
__global__ void k0_w2(const float* __restrict__ wf, const float* __restrict__ wb,
                      float* __restrict__ ws) {
    int c = blockIdx.x, t = blockIdx.y;
    const float* w = t ? wb : wf;
    uint16_t* w2 = (uint16_t*)(ws + OFF_WT);
    int tid = threadIdx.x;
    int lane = tid & 63, dq = tid >> 6;
    int d = dq * 16 + (lane & 15), quad = lane >> 4;
    for (int kci = 0; kci < 2; ++kci) {
        int k = kci * 32 + quad * 8;
        const float* src = w + (size_t)(d * 64 + c) * 64 + k;
        uint16_t hb[8], lb[8];
#pragma unroll
        for (int j = 0; j < 8; ++j) split_bf16(src[j], hb[j], lb[j]);
        size_t base = ((size_t)(((t * 64 + c) * 2 + kci) * 4 + dq) * 2) * 512 + lane * 8;
        *(uint4*)(w2 + base) = pack8(hb);
        *(uint4*)(w2 + base + 512) = pack8(lb);
    }
}

// ---------------- K1: per-patch fg/bg stats ----------------
__global__ void k1_stats(const float* __restrict__ x, const float* __restrict__ mask,
                         float* __restrict__ ws) {
    int i = blockIdx.x, c = blockIdx.y, b = blockIdx.z;
    __shared__ float xs[8 * 256];
    __shared__ float ms[8 * 256];
    __shared__ float pS[5][256];
    int t = threadIdx.x;
    const float* xr = x + (((b * 64 + c) * 256) + i * 4) * 256;
    const float* mr = mask + (b * 256 + i * 4) * 256;
#pragma unroll
    for (int r = 0; r < 8; ++r) {
        xs[r * 256 + t] = xr[r * 256 + t];
        ms[r * 256 + t] = mr[r * 256 + t];
    }
    __syncthreads();
    int q = t >> 6, j = t & 63;
    float Sa = 0, Qa = 0, Sf = 0, Qf = 0, Nf = 0;
    if (j < 63) {
#pragma unroll
        for (int rr = 0; rr < 2; ++rr) {
            int base = (q * 2 + rr) * 256 + j * 4;
#pragma unroll
            for (int cc = 0; cc < 8; ++cc) {
                float v = xs[base + cc], m = ms[base + cc];
                Sa += v; Qa += v * v; Sf += v * m; Qf += v * v * m; Nf += m;
            }
        }
    }
    pS[0][t] = Sa; pS[1][t] = Qa; pS[2][t] = Sf; pS[3][t] = Qf; pS[4][t] = Nf;
    __syncthreads();
    if (q == 0 && j < 63) {
        Sa = pS[0][j] + pS[0][j + 64] + pS[0][j + 128] + pS[0][j + 192];
        Qa = pS[1][j] + pS[1][j + 64] + pS[1][j + 128] + pS[1][j + 192];
        Sf = pS[2][j] + pS[2][j + 64] + pS[2][j + 128] + pS[2][j + 192];
        Qf = pS[3][j] + pS[3][j + 64] + pS[3][j + 128] + pS[3][j + 192];
        Nf = pS[4][j] + pS[4][j + 64] + pS[4][j + 128] + pS[4][j + 192];
        float nb = 64.0f - Nf;
        float muf = Sf / (Nf + EPS_);
        float vaf = (Qf - 2.f * muf * Sf + Nf * muf * muf) / (Nf + EPS_);
        float Sb = Sa - Sf, Qb = Qa - Qf;
        float mub = Sb / (nb + EPS_);
        float vab = (Qb - 2.f * mub * Sb + nb * mub * mub) / (nb + EPS_);
        int idx = (b * 64 + c) * LP + i * 63 + j;
        ws[OFF_MF + idx] = muf; ws[OFF_SF + idx] = vaf;
        ws[OFF_MB + idx] = mub; ws[OFF_SB + idx] = vab;
    }
}

// ---------------- K2: split-bf16 MFMA tok GEMM, t factored into the grid ----------------
// grid (63 il, 8 = 4 kc x 2 t, 2 b), 256 threads, 1008 blocks (~4/CU).
// Each block computes ONE stream (fore or back) with R8's proven 1-barrier-per-
// channel pipeline. LDS = 2 dbuf x 2 planes = 36 KB -> 4 blocks/CU capacity,
// now matched by grid supply. x re-read by the other stream's blocks is
// L3-resident (33.5 MB << 256 MB).
__global__ __launch_bounds__(256, 4)
void k2_tok(const float* __restrict__ x, const float* __restrict__ mask,
            const float* __restrict__ wsc, float* __restrict__ ws) {
    int il = blockIdx.x;
    int kc = blockIdx.y & 3, ts = blockIdx.y >> 2;   // ts: 0 = fore, 1 = back
    int b = blockIdx.z;
    int tid = threadIdx.x;
    int jl = tid & 63;
    int q = tid >> 6;
    __shared__ uint16_t IN[2][2 * 64 * 72];   // [buffer][hl plane][l 64][k 72pad] = 36 KB
    const uint16_t* w2 = (const uint16_t*)(wsc + OFF_WT);

    bool lv = jl < 63;
    int lg = il * 63 + jl;

    uint32_t mbits[2] = {0u, 0u};
    if (lv) {
#pragma unroll
        for (int oi = 0; oi < 2; ++oi) {
            int o = q + oi * 4;
            const float* mp = mask + (size_t)b * 65536 + (il * 4 + o) * 256 + jl * 4;
            float4 m0 = *(const float4*)mp;
            float4 m1 = *(const float4*)(mp + 4);
            uint32_t bits = 0;
            bits |= (m0.x != 0.f) ? 1u : 0u;  bits |= (m0.y != 0.f) ? 2u : 0u;
            bits |= (m0.z != 0.f) ? 4u : 0u;  bits |= (m0.w != 0.f) ? 8u : 0u;
            bits |= (m1.x != 0.f) ? 16u : 0u; bits |= (m1.y != 0.f) ? 32u : 0u;
            bits |= (m1.z != 0.f) ? 64u : 0u; bits |= (m1.w != 0.f) ? 128u : 0u;
            mbits[oi] = bits;
        }
    }

    f32x4 acc[2][2];   // [dqi][lt]
#pragma unroll
    for (int i2 = 0; i2 < 2; ++i2)
#pragma unroll
        for (int j2 = 0; j2 < 2; ++j2) acc[i2][j2] = (f32x4)(0.f);

    int lane = tid & 63;
    int quad = lane >> 4;
    int c16 = lane & 15;
    int wd = q >> 1, wl = q & 1;   // wave tile: d half, l half
    int c0 = kc * 16;

    const size_t off_mu = ts ? OFF_MB : OFF_MF;
    const size_t off_va = ts ? OFF_SB : OFF_SF;

    float4 xa[2][2];   // [oi][half]
    if (!lv) {
        xa[0][0] = xa[0][1] = xa[1][0] = xa[1][1] = make_float4(0.f, 0.f, 0.f, 0.f);
    }
    float mu = 0.f, va = 1.f;

#define K2_LOADCH(cc)                                                                \
    do {                                                                             \
        if (lv) {                                                                    \
            int si = (b * 64 + (cc)) * LP + lg;                                      \
            mu = wsc[off_mu + si]; va = wsc[off_va + si];                            \
            const float* xp0 = x + (size_t)(b * 64 + (cc)) * 65536 + (il * 4 + q) * 256 + jl * 4; \
            xa[0][0] = *(const float4*)xp0;                                          \
            xa[0][1] = *(const float4*)(xp0 + 4);                                    \
            xa[1][0] = *(const float4*)(xp0 + 1024);                                 \
            xa[1][1] = *(const float4*)(xp0 + 1028);                                 \
        }                                                                            \
    } while (0)

    // pack this block's stream into buffer 'bufsel'. jl==63 lanes stage exact 0.
#define K2_PACK(bufsel)                                                              \
    do {                                                                             \
        float inv_ = lv ? (1.0f / va) : 0.f;                                         \
        float cm_ = lv ? mu : 0.f;                                                   \
        _Pragma("unroll")                                                            \
        for (int oi = 0; oi < 2; ++oi) {                                             \
            float xv[8];                                                             \
            xv[0] = xa[oi][0].x; xv[1] = xa[oi][0].y;                                \
            xv[2] = xa[oi][0].z; xv[3] = xa[oi][0].w;                                \
            xv[4] = xa[oi][1].x; xv[5] = xa[oi][1].y;                                \
            xv[6] = xa[oi][1].z; xv[7] = xa[oi][1].w;                                \
            float fv[8];                                                             \
            _Pragma("unroll")                                                        \
            for (int j = 0; j < 8; ++j) {                                            \
                bool mf = (mbits[oi] >> j) & 1;                                      \
                float nrm = (xv[j] - cm_) * inv_;                                    \
                fv[j] = ts ? (mf ? cm_ : nrm) : (mf ? nrm : cm_);                    \
            }                                                                        \
            uint4 H, L;                                                              \
            H.x = pkhi2(fv[0], fv[1]); H.y = pkhi2(fv[2], fv[3]);                    \
            H.z = pkhi2(fv[4], fv[5]); H.w = pkhi2(fv[6], fv[7]);                    \
            L.x = pklo2(fv[0], fv[1]); L.y = pklo2(fv[2], fv[3]);                    \
            L.z = pklo2(fv[4], fv[5]); L.w = pklo2(fv[6], fv[7]);                    \
            uint16_t* dst = &IN[bufsel][jl * 72 + (q + oi * 4) * 8];                 \
            *(uint4*)(dst)        = H;                                               \
            *(uint4*)(dst + 4608) = L;                                               \
        }                                                                            \
    } while (0)

    // MFMA this block's stream of channel cch from buffer bufi (24 MFMAs/wave)
#define K2_MFMA(bufi, cch)                                                           \
    do {                                                                             \
        _Pragma("unroll")                                                            \
        for (int kci = 0; kci < 2; ++kci) {                                          \
            bf16x8 Ah[2], Al[2];                                                     \
            _Pragma("unroll")                                                        \
            for (int dqi = 0; dqi < 2; ++dqi) {                                      \
                const uint16_t* ab = w2 +                                            \
                    ((size_t)(((ts * 64 + (cch)) * 2 + kci) * 4 + (wd * 2 + dqi)) * 2) * 512 + lane * 8; \
                Ah[dqi] = *(const bf16x8*)ab;                                        \
                Al[dqi] = *(const bf16x8*)(ab + 512);                                \
            }                                                                        \
            _Pragma("unroll")                                                        \
            for (int lt = 0; lt < 2; ++lt) {                                         \
                const uint16_t* bp = &IN[bufi][(wl * 32 + lt * 16 + c16) * 72 + kci * 32 + quad * 8]; \
                bf16x8 Bh = *(const bf16x8*)bp;                                      \
                bf16x8 Bl = *(const bf16x8*)(bp + 4608);                             \
                _Pragma("unroll")                                                    \
                for (int dqi = 0; dqi < 2; ++dqi) {                                  \
                    acc[dqi][lt] = __builtin_amdgcn_mfma_f32_16x16x32_bf16(Ah[dqi], Bh, acc[dqi][lt], 0, 0, 0); \
                    acc[dqi][lt] = __builtin_amdgcn_mfma_f32_16x16x32_bf16(Ah[dqi], Bl, acc[dqi][lt], 0, 0, 0); \
                    acc[dqi][lt] = __builtin_amdgcn_mfma_f32_16x16x32_bf16(Al[dqi], Bh, acc[dqi][lt], 0, 0, 0); \
                }                                                                    \
            }                                                                        \
        }                                                                            \
    } while (0)

    // prologue: stage channel c0 into buffer 0, prefetch c0+1
    K2_LOADCH(c0);
    K2_PACK(0);
    K2_LOADCH(c0 + 1);
    __syncthreads();

    // steady state: one barrier per channel (R8's proven discipline)
#pragma unroll 2
    for (int ci = 0; ci < 16; ++ci) {
        int cur = ci & 1;
        if (ci < 15) {
            K2_PACK(cur ^ 1);              // pack channel ci+1
            if (ci < 14) K2_LOADCH(c0 + ci + 2);
        }
        K2_MFMA(cur, c0 + ci);
        __syncthreads();
    }
#undef K2_LOADCH
#undef K2_PACK
#undef K2_MFMA

    // ---- epilogue: LDS transpose -> coalesced float4 stores to PART slice ----
    // C/D 16x16: row(d within tile)=quad*4+r, col(l within tile)=lane&15
    float* ST = (float*)&IN[0][0];   // 64 l x 68 d floats = 17.4 KB <= IN[0] (18.4 KB)
#pragma unroll
    for (int dqi = 0; dqi < 2; ++dqi)
#pragma unroll
        for (int lt = 0; lt < 2; ++lt)
#pragma unroll
            for (int r = 0; r < 4; ++r)
                ST[(wl * 32 + lt * 16 + c16) * 68 + (wd * 2 + dqi) * 16 + quad * 4 + r] =
                    acc[dqi][lt][r];
    __syncthreads();
    float* dst = ws + OFF_TOKF + (size_t)kc * PART_SLICE + ((ts * 2 + b) * (size_t)LP) * 64;
    int d4 = (tid & 15) * 4;
#pragma unroll
    for (int pass = 0; pass < 4; ++pass) {
        int l = pass * 16 + (tid >> 4);
        if (l < 63)
            *(float4*)&dst[(size_t)(il * 63 + l) * 64 + d4] = *(float4*)&ST[l * 68 + d4];
    }
}

// ---------------- K2r: reduce 4 kc partial slices -> separated bf16 planes ----------------
// TF planes (t=0): [b*2+hl][PLANE] u16 at OFF_SB  (SB f32 dead after k1s; exact fit)
// TB planes (t=1): [b*2+hl][PLANE] u16 at OFF_WT  (weights dead after k2; fits)
__global__ void k2r_reduce(float* __restrict__ ws) {
    size_t e = ((size_t)blockIdx.x * 256 + threadIdx.x) * 4;
    float4 a0 = *(float4*)&ws[OFF_TOKF + e];
    float4 a1 = *(float4*)&ws[OFF_TOKF + PART_SLICE + e];
    float4 a2 = *(float4*)&ws[OFF_TOKF + 2 * PART_SLICE + e];
    float4 a3 = *(float4*)&ws[OFF_TOKF + 3 * PART_SLICE + e];
    float s0 = a0.x + a1.x + a2.x + a3.x;
    float s1 = a0.y + a1.y + a2.y + a3.y;
    float s2 = a0.z + a1.z + a2.z + a3.z;
    float s3 = a0.w + a1.w + a2.w + a3.w;
    int tb = (int)(e / (size_t)PLANE);           // t*2+b  (element order is [t][b][LP][64])
    int idx = (int)(e - (size_t)tb * PLANE);
    int t = tb >> 1, b = tb & 1;
    uint16_t* pl = (uint16_t*)(ws + (t ? OFF_WT : OFF_SB));
    uint2 hv, lv;
    hv.x = pkhi2(s0, s1); hv.y = pkhi2(s2, s3);
    lv.x = pklo2(s0, s1); lv.y = pklo2(s2, s3);
    *(uint2*)&pl[(size_t)(b * 2 + 0) * PLANE + idx] = hv;
    *(uint2*)&pl[(size_t)(b * 2 + 1) * PLANE + idx] = lv;
}

// ---------------- K1s: SB variances -> bf16 tiles [b][im][c][64] (m=63 zeroed) ----------
// Runs after k2 (which reads MB/SB f32) and BEFORE k2r (which overwrites SB f32).
__global__ void k1s_sb(float* __restrict__ ws) {
    int im = blockIdx.x, b = blockIdx.y;
    int tid = threadIdx.x;
    int c = tid >> 2, mm = (tid & 3) * 16;
    const float* src = ws + OFF_SB + ((size_t)b * 64 + c) * LP + im * 63 + mm;
    uint16_t sv[16];
#pragma unroll
    for (int u = 0; u < 16; ++u)
        sv[u] = (mm + u < 63) ? bf16_rne(src[u]) : (uint16_t)0;
    uint16_t* dst = (uint16_t*)(ws + OFF_MB) + (((size_t)b * 63 + im) * 64 + c) * 64 + mm;
    *(uint4*)(dst) = pack8(sv);
    *(uint4*)(dst + 8) = pack8(sv + 8);
}

// ---------------- K3: swapped-QK^T MFMA flash attention ----------------
// grid (63 il, MH imc, 2 b), 256 threads, 4 blocks/CU (37.4 KB LDS).
// Q (tok_f) fragments live in registers (wave-private rows). QK^T computes
// mfma(A=keys, B=queries) so each lane owns one query's score row -> softmax
// reduce = in-lane tree + 2 shfls (vs 32 shfls). P has a dedicated wave-private
// LDS buffer -> only 2 barriers/iter. T14 prefetch retained.
__global__ __launch_bounds__(256, 4)
void k3_attn(const float* __restrict__ wsc, const float* __restrict__ rpb,
             float* __restrict__ ws) {
    int il = blockIdx.x, imc = blockIdx.y, b = blockIdx.z;
    int tid = threadIdx.x;
    int w = tid >> 6, lane = tid & 63;
    int c16 = lane & 15, quad = lane >> 4;

    __shared__ uint16_t TBh[64 * 72];   // tok_b hi [m][c]
    __shared__ uint16_t TBl[64 * 72];   // tok_b lo
    __shared__ uint16_t SB[64 * 72];    // sb [c][m] bf16
    __shared__ uint16_t P[64 * 72];     // P [query][m] (wave-private 16-row stripes)
    __shared__ float bias_r[128];

    const uint16_t* tfp = (const uint16_t*)(wsc + OFF_SB);
    const uint16_t* tbp = (const uint16_t*)(wsc + OFF_WT);
    const uint16_t* TFH = tfp + (size_t)(b * 2 + 0) * PLANE;
    const uint16_t* TFL = tfp + (size_t)(b * 2 + 1) * PLANE;
    const uint16_t* TBH = tbp + (size_t)(b * 2 + 0) * PLANE;
    const uint16_t* TBL = tbp + (size_t)(b * 2 + 1) * PLANE;
    const uint16_t* sbb = (const uint16_t*)(wsc + OFF_MB);    // [b][im][c][64] bf16

    // Q fragments (B-operand rows = query = lane&15), loaded once from planes.
    int qrow = il * 63 + w * 16 + c16;   // rows 3969..3971 garbage only for discarded query
    bf16x8 Qh[2], Ql[2];
#pragma unroll
    for (int kk = 0; kk < 2; ++kk) {
        Qh[kk] = *(const bf16x8*)&TFH[(size_t)qrow * 64 + kk * 32 + quad * 8];
        Ql[kk] = *(const bf16x8*)&TFL[(size_t)qrow * 64 + kk * 32 + quad * 8];
    }

    float mrun = -1e30f, drun = 0.f;     // per-lane: one query (w*16+c16)
    f32x4 acc2[4];
#pragma unroll
    for (int ct = 0; ct < 4; ++ct) acc2[ct] = (f32x4)(0.f);

    int im0 = imc * IMR;
    int im1 = min(63, im0 + IMR);

    // T14 prefetch registers
    int jms = tid >> 2, ccs = (tid & 3) * 16;
    uint4 rTH0, rTH1, rTL0, rTL1, rS0, rS1;
    float rBias;

#define K3_PREFETCH(imv)                                                              \
    do {                                                                              \
        if (jms < 63) {                                                               \
            const uint16_t* sh_ = TBH + (size_t)((imv) * 63 + jms) * 64 + ccs;        \
            const uint16_t* sl_ = TBL + (size_t)((imv) * 63 + jms) * 64 + ccs;        \
            rTH0 = *(const uint4*)sh_; rTH1 = *(const uint4*)(sh_ + 8);               \
            rTL0 = *(const uint4*)sl_; rTL1 = *(const uint4*)(sl_ + 8);               \
        } else {                                                                      \
            rTH0 = rTH1 = rTL0 = rTL1 = make_uint4(0u,0u,0u,0u);                      \
        }                                                                             \
        const uint16_t* ss_ = sbb + (((size_t)b * 63 + (imv)) * 64 + jms) * 64 + ccs; \
        rS0 = *(const uint4*)ss_; rS1 = *(const uint4*)(ss_ + 8);                     \
        rBias = (tid < 125) ? rpb[(il - (imv) + 62) * 125 + tid] : 0.f;               \
    } while (0)

    K3_PREFETCH(im0);

    int ibias = w * 16 + c16 + 62 - quad * 4;   // bias idx = ibias - jt*16 - r

    for (int im = im0; im < im1; ++im) {
        __syncthreads();   // previous tile's readers done
        *(uint4*)&TBh[jms * 72 + ccs] = rTH0; *(uint4*)&TBh[jms * 72 + ccs + 8] = rTH1;
        *(uint4*)&TBl[jms * 72 + ccs] = rTL0; *(uint4*)&TBl[jms * 72 + ccs + 8] = rTL1;
        *(uint4*)&SB[jms * 72 + ccs]  = rS0;  *(uint4*)&SB[jms * 72 + ccs + 8]  = rS1;
        if (tid < 128) bias_r[tid] = rBias;
        if (im + 1 < im1) K3_PREFETCH(im + 1);
        __syncthreads();

        // ---- QK^T swapped: A = keys (LDS), B = queries (regs) ----
        // D rows = m (quad*4+r per 16-tile jt), cols = query (c16)
        f32x4 Z[4];
#pragma unroll
        for (int jt = 0; jt < 4; ++jt) Z[jt] = (f32x4)(0.f);
#pragma unroll
        for (int jt = 0; jt < 4; ++jt) {
#pragma unroll
            for (int kk = 0; kk < 2; ++kk) {
                bf16x8 Kh = *(bf16x8*)&TBh[(jt * 16 + c16) * 72 + kk * 32 + quad * 8];
                bf16x8 Kl = *(bf16x8*)&TBl[(jt * 16 + c16) * 72 + kk * 32 + quad * 8];
                Z[jt] = __builtin_amdgcn_mfma_f32_16x16x32_bf16(Kh, Qh[kk], Z[jt], 0, 0, 0);
                Z[jt] = __builtin_amdgcn_mfma_f32_16x16x32_bf16(Kh, Ql[kk], Z[jt], 0, 0, 0);
                Z[jt] = __builtin_amdgcn_mfma_f32_16x16x32_bf16(Kl, Qh[kk], Z[jt], 0, 0, 0);
            }
        }

        // ---- bias + mask: lane owns query w*16+c16, scores over m ----
        float zv[4][4];
#pragma unroll
        for (int jt = 0; jt < 4; ++jt)
#pragma unroll
            for (int r = 0; r < 4; ++r) {
                int m = jt * 16 + quad * 4 + r;
                int bi = ibias - jt * 16 - r;
                bi = bi < 0 ? 0 : bi;            // binds only on the masked (i=0,m=63) lane
                zv[jt][r] = (m == 63) ? -1e30f : (Z[jt][r] + bias_r[bi]);
            }

        // ---- softmax: in-lane tree + xor16/xor32 (c16-preserving) ----
        float a0 = fmaxf(zv[0][0], zv[0][1]), a1 = fmaxf(zv[0][2], zv[0][3]);
        float a2 = fmaxf(zv[1][0], zv[1][1]), a3 = fmaxf(zv[1][2], zv[1][3]);
        float a4 = fmaxf(zv[2][0], zv[2][1]), a5 = fmaxf(zv[2][2], zv[2][3]);
        float a6 = fmaxf(zv[3][0], zv[3][1]), a7 = fmaxf(zv[3][2], zv[3][3]);
        a0 = fmaxf(a0, a1); a2 = fmaxf(a2, a3); a4 = fmaxf(a4, a5); a6 = fmaxf(a6, a7);
        float vmax = fmaxf(fmaxf(a0, a2), fmaxf(a4, a6));
        vmax = fmaxf(vmax, __shfl_xor(vmax, 16));
        vmax = fmaxf(vmax, __shfl_xor(vmax, 32));
        float mnew = fmaxf(mrun, vmax);
        float alpha = exp2f((mrun - mnew) * LOG2E);
        uint16_t pb[4][4];
        float sv[8];
#pragma unroll
        for (int jt = 0; jt < 4; ++jt) {
            float p0 = exp2f((zv[jt][0] - mnew) * LOG2E);
            float p1 = exp2f((zv[jt][1] - mnew) * LOG2E);
            float p2 = exp2f((zv[jt][2] - mnew) * LOG2E);
            float p3 = exp2f((zv[jt][3] - mnew) * LOG2E);
            uint16_t h0 = bf16_rne(p0), h1 = bf16_rne(p1);
            uint16_t h2 = bf16_rne(p2), h3 = bf16_rne(p3);
            pb[jt][0] = h0; pb[jt][1] = h1; pb[jt][2] = h2; pb[jt][3] = h3;
            sv[jt * 2]     = __uint_as_float((uint32_t)h0 << 16) + __uint_as_float((uint32_t)h1 << 16);
            sv[jt * 2 + 1] = __uint_as_float((uint32_t)h2 << 16) + __uint_as_float((uint32_t)h3 << 16);
        }
        float s = ((sv[0] + sv[1]) + (sv[2] + sv[3])) + ((sv[4] + sv[5]) + (sv[6] + sv[7]));
        s += __shfl_xor(s, 16);
        s += __shfl_xor(s, 32);
        drun = drun * alpha + s;
        mrun = mnew;

        // redistribute alpha to accumulator row decomposition (D rows = quad*4+r)
        float alphav[4];
#pragma unroll
        for (int r = 0; r < 4; ++r) alphav[r] = __shfl(alpha, quad * 4 + r, 16);
#pragma unroll
        for (int ct = 0; ct < 4; ++ct)
#pragma unroll
            for (int r = 0; r < 4; ++r) acc2[ct][r] *= alphav[r];

        // ---- P write: row = query (w*16+c16), cols m; wave-private, packed b64 ----
#pragma unroll
        for (int jt = 0; jt < 4; ++jt) {
            uint2 pw;
            pw.x = (uint32_t)pb[jt][0] | ((uint32_t)pb[jt][1] << 16);
            pw.y = (uint32_t)pb[jt][2] | ((uint32_t)pb[jt][3] << 16);
            *(uint2*)&P[(w * 16 + c16) * 72 + jt * 16 + quad * 4] = pw;
        }
        asm volatile("" ::: "memory");

        // ---- PV: A = P (rows=query), B = SB (rows=channel) ----
#pragma unroll
        for (int kk = 0; kk < 2; ++kk) {
            bf16x8 Pf = *(bf16x8*)&P[(w * 16 + c16) * 72 + kk * 32 + quad * 8];
#pragma unroll
            for (int ct = 0; ct < 4; ++ct) {
                bf16x8 Sf = *(bf16x8*)&SB[(ct * 16 + c16) * 72 + kk * 32 + quad * 8];
                acc2[ct] = __builtin_amdgcn_mfma_f32_16x16x32_bf16(Pf, Sf, acc2[ct], 0, 0, 0);
            }
        }
        asm volatile("" ::: "memory");   // keep next iter's P writes after these reads
    }

    float* PA = ws + OFF_PACC + ((imc * 2 + b) * (size_t)LP) * 64;
#pragma unroll
    for (int r = 0; r < 4; ++r) {
        int i = w * 16 + quad * 4 + r;
        if (i < 63) {
            int rl = il * 63 + i;
#pragma unroll
            for (int ct = 0; ct < 4; ++ct)
                PA[(size_t)rl * 64 + ct * 16 + c16] = acc2[ct][r];
        }
    }
    if (quad == 0) {
        int i = w * 16 + c16;
        if (i < 63) {
            int rl = il * 63 + i;
            ws[OFF_PM + (imc * 2 + b) * LP + rl] = mrun;
            ws[OFF_PD + (imc * 2 + b) * LP + rl] = drun;
        }
    }
#undef K3_PREFETCH
}

// ---------------- K3b: merge the MH m-slices; result lands in PACC slice 0 ----------------
__global__ void k3b_merge(float* __restrict__ ws) {
    int b = blockIdx.y;
    int l = blockIdx.x * 4 + (threadIdx.x >> 6);
    int c = threadIdx.x & 63;
    if (l >= L_) return;
    float M = -1e30f;
#pragma unroll
    for (int p = 0; p < MH; ++p)
        M = fmaxf(M, ws[OFF_PM + (p * 2 + b) * LP + l]);
    float denom = 0.f, num = 0.f;
#pragma unroll
    for (int p = 0; p < MH; ++p) {
        float w = exp2f((ws[OFF_PM + (p * 2 + b) * LP + l] - M) * LOG2E);
        denom += ws[OFF_PD + (p * 2 + b) * LP + l] * w;
        num += ws[OFF_PACC + ((p * 2 + b) * (size_t)LP + l) * 64 + c] * w;
    }
    ws[OFF_PACC + (b * (size_t)LP + l) * 64 + c] = num / denom;
}

// ---------------- K3c: fold coefficients A = NS/SF, B = NS - MF*A, C = NS*(MF+1) ----------------
__global__ void k3c_coef(float* __restrict__ ws) {
    int b = blockIdx.y;
    int bl = blockIdx.x;
    int tid = threadIdx.x;
    __shared__ float T[3][4][65];
    int ls = tid >> 6, c = tid & 63;
    int l = bl * 4 + ls;
    float ns = ws[OFF_PACC + ((size_t)b * LP + l) * 64 + c];
    float mf = ws[OFF_MF + (size_t)(b * 64 + c) * LP + l];
    float sf = ws[OFF_SF + (size_t)(b * 64 + c) * LP + l];
    float a = ns / sf;
    T[0][ls][c] = a;
    T[1][ls][c] = ns - mf * a;
    T[2][ls][c] = ns * (mf + 1.f);
    __syncthreads();
    int c2 = tid >> 2, l2 = tid & 3;
    size_t o = (size_t)(b * 64 + c2) * LP + bl * 4 + l2;
    ws[OFF_A + o] = T[0][l2][c2];
    ws[OFF_B + o] = T[1][l2][c2];
    ws[OFF_C + o] = T[2][l2][c2];
}

// ---------------- K4: fold + affines + compose output (coefficient form, no divides) ----------------
__global__ void k4_fold(const float* __restrict__ x, const float* __restrict__ mask,
                        const float* __restrict__ fg_g, const float* __restrict__ fg_b,
                        const float* __restrict__ bg_g, const float* __restrict__ bg_b,
                        const float* __restrict__ wsc, float* __restrict__ out) {
    int gid = blockIdx.x * 256 + threadIdx.x;
    int col = gid & 255, r = (gid >> 8) & 255, c = (gid >> 16) & 63, b = gid >> 22;
    float xv = x[gid];
    float m = mask[b * 65536 + r * 256 + col];
    int imin = (r >= 4) ? ((r - 4) >> 2) : 0;
    int imax = min(62, r >> 2);
    int jmin = (col >= 4) ? ((col - 4) >> 2) : 0;
    int jmax = min(62, col >> 2);
    bool fi = imax > imin, fj = jmax > jmin;
    int l00 = imin * 63 + jmin;
    const float* Aa = wsc + OFF_A + (size_t)(b * 64 + c) * LP;
    const float* Ba = wsc + OFF_B + (size_t)(b * 64 + c) * LP;
    const float* Ca = wsc + OFF_C + (size_t)(b * 64 + c) * LP;
    float a00 = Aa[l00],      b00 = Ba[l00],      c00 = Ca[l00];
    float a01 = Aa[l00 + 1],  b01 = Ba[l00 + 1],  c01 = Ca[l00 + 1];
    float a10 = Aa[l00 + 63], b10 = Ba[l00 + 63], c10 = Ca[l00 + 63];
    float a11 = Aa[l00 + 64], b11 = Ba[l00 + 64], c11 = Ca[l00 + 64];
    bool fij = fi && fj;
    float SA = a00 + (fj ? a01 : 0.f) + (fi ? a10 : 0.f) + (fij ? a11 : 0.f);
    float SBv = b00 + (fj ? b01 : 0.f) + (fi ? b10 : 0.f) + (fij ? b11 : 0.f);
    float SCv = c00 + (fj ? c01 : 0.f) + (fi ? c10 : 0.f) + (fij ? c11 : 0.f);
    float folded = (m != 0.f) ? (xv * SA + SBv) : SCv;
    float rc = (fi ? 0.5f : 1.f) * (fj ? 0.5f : 1.f);
    float invm = 1.f - m;
    float ub = (xv * invm * (1.f + bg_g[c]) + bg_b[c]) * invm;
    float nf = (folded * rc * (1.f + fg_g[c]) + fg_b[c]) * m;
    out[gid] = nf + ub;
}

extern "C" void kernel_launch(void* const* d_in, const int* in_sizes, int n_in,
                              void* d_out, int out_size, void* d_ws, size_t ws_size,
                              hipStream_t stream) {
    const float* x    = (const float*)d_in[0];
    const float* mask = (const float*)d_in[1];
    const float* fg_g = (const float*)d_in[2];
    const float* fg_b = (const float*)d_in[3];
    const float* bg_g = (const float*)d_in[4];
    const float* bg_b = (const float*)d_in[5];
    const float* wf   = (const float*)d_in[6];
    const float* wb   = (const float*)d_in[7];
    const float* rpb  = (const float*)d_in[8];
    float* ws = (float*)d_ws;
    float* out = (float*)d_out;

    k0_w2<<<dim3(64, 2), 256, 0, stream>>>(wf, wb, ws);
    k1_stats<<<dim3(63, 64, 2), 256, 0, stream>>>(x, mask, ws);
    k2_tok<<<dim3(63, 8, 2), 256, 0, stream>>>(x, mask, ws, ws);
    k1s_sb<<<dim3(63, 2), 256, 0, stream>>>(ws);          // before k2r (k2r overwrites SB f32)
    k2r_reduce<<<dim3(993), 256, 0, stream>>>(ws);
    k3_attn<<<dim3(63, MH, 2), 256, 0, stream>>>(ws, rpb, ws);
    k3b_merge<<<dim3(993, 2), 256, 0, stream>>>(ws);
    k3c_coef<<<dim3(993, 2), 256, 0, stream>>>(ws);
    k4_fold<<<dim3(32768), 256, 0, stream>>>(x, mask, fg_g, fg_b, bg_g, bg_b, ws, out);
}